// Round 10
// baseline (903.895 us; speedup 1.0000x reference)
//
#include <hip/hip_runtime.h>
#include <hip/hip_bf16.h>

// ---------------------------------------------------------------------------
// SpMiddlePillarEncoder8x18. Round 10: LDS-byte reduction. B weights are
// pre-permuted into MFMA fragment order ([tap][nb][kc][kh][nf][lane]x16B) and
// loaded global->VGPR (coalesced, imm offsets), double-buffered, 2-step
// prefetch; A stays in a 3-slot LDS ring (48KB). Per step: wait vmcnt(12)
// [retires A(s)+B(s); A(s+1),B(s+1) stay in flight]; barrier; issue A(s+2);
// compute(s); load B(s+2) after the MFMA cluster. LDS pipe traffic halves.
// ---------------------------------------------------------------------------

typedef __attribute__((ext_vector_type(8))) short bf16x8;
typedef __attribute__((ext_vector_type(4))) float f32x4;
typedef unsigned short u16;

#define GLD16(g, l)                                                   \
    __builtin_amdgcn_global_load_lds(                                 \
        (const __attribute__((address_space(1))) void*)(g),           \
        (__attribute__((address_space(3))) void*)(l), 16, 0, 0)

#define SB0 __builtin_amdgcn_sched_barrier(0)

__device__ __forceinline__ u16 f2b(float f) {
    unsigned u = __float_as_uint(f);
    u += 0x7fffu + ((u >> 16) & 1u);  // round-to-nearest-even
    return (u16)(u >> 16);
}
__device__ __forceinline__ float b2f(u16 h) {
    return __uint_as_float(((unsigned)h) << 16);
}

// ------------------------------- binning -----------------------------------
__global__ __launch_bounds__(256) void bin_kernel(
    const float* __restrict__ xyz, const int* __restrict__ cnt,
    int* __restrict__ pcnt, int* __restrict__ plist, int N) {
    int i = blockIdx.x * 256 + threadIdx.x;
    if (i >= N) return;
    float x = xyz[3 * i], y = xyz[3 * i + 1];
    int b = (i < cnt[0]) ? 0 : 1;
    int ix = (int)floorf((x + 75.2f) / 0.8f);
    int iy = (int)floorf((y + 75.2f) / 0.8f);
    ix = min(max(ix, 0), 187);
    iy = min(max(iy, 0), 187);
    int flat = (b * 188 + iy) * 188 + ix;
    int slot = atomicAdd(pcnt + flat, 1);
    if (slot < 32) plist[flat * 32 + slot] = i;
}

// --------------------------- pillar MLP + max ------------------------------
__global__ __launch_bounds__(256) void pillar_kernel(
    const float* __restrict__ xyz, const float* __restrict__ ptf,
    const float* __restrict__ mw, const float* __restrict__ mg,
    const float* __restrict__ mb, const int* __restrict__ pcnt,
    const int* __restrict__ plist, u16* __restrict__ out,
    float* __restrict__ occ) {
    const int lane = threadIdx.x & 63, wid = threadIdx.x >> 6;
    const int p = blockIdx.x * 4 + wid;
    const int n = min(pcnt[p], 32);
    const int c = lane * 4;
    float m0 = 0.f, m1 = 0.f, m2 = 0.f, m3 = 0.f;
    if (n > 0) {
        const int ix = p % 188;
        const int iy = (p / 188) % 188;
        const float cx = -75.2f + ((float)ix + 0.5f) * 0.8f;
        const float cy = -75.2f + ((float)iy + 0.5f) * 0.8f;
        float4 w[8];
#pragma unroll
        for (int k = 0; k < 8; k++) w[k] = *(const float4*)(mw + k * 256 + c);
        for (int t = 0; t < n; t++) {
            int i = __builtin_amdgcn_readfirstlane(plist[p * 32 + t]);
            float x = xyz[3 * i], y = xyz[3 * i + 1], z = xyz[3 * i + 2];
            float f0 = ptf[2 * i], f1 = ptf[2 * i + 1];
            const float f[8] = {x, y, z, x - cx, y - cy, z, f0, f1};
            float s0 = 0.f, s1 = 0.f, s2 = 0.f, s3 = 0.f;
#pragma unroll
            for (int k = 0; k < 8; k++) {
                s0 = fmaf(f[k], w[k].x, s0);
                s1 = fmaf(f[k], w[k].y, s1);
                s2 = fmaf(f[k], w[k].z, s2);
                s3 = fmaf(f[k], w[k].w, s3);
            }
            float4 g4 = *(const float4*)(mg + c);
            float4 b4 = *(const float4*)(mb + c);
            m0 = fmaxf(m0, fmaxf(s0 * g4.x + b4.x, 0.f));
            m1 = fmaxf(m1, fmaxf(s1 * g4.y + b4.y, 0.f));
            m2 = fmaxf(m2, fmaxf(s2 * g4.z + b4.z, 0.f));
            m3 = fmaxf(m3, fmaxf(s3 * g4.w + b4.w, 0.f));
        }
    }
    unsigned lo = (unsigned)f2b(m0) | ((unsigned)f2b(m1) << 16);
    unsigned hi = (unsigned)f2b(m2) | ((unsigned)f2b(m3) << 16);
    *(uint2*)(out + (size_t)p * 256 + c) = make_uint2(lo, hi);
    if (lane == 0) occ[p] = (n > 0) ? 1.f : 0.f;
}

// ---------------- weight convert into FRAGMENT layout (once) ---------------
// src: [mat][c][n] f32 (mat = layer*9+tap). dst (per mat, 65536 u16):
// idx = ((((nb*4+kc)*2+kh)*4+nf)*64 + lane)*8 + e  holds
// W[c = kc*64+kh*32+(lane>>4)*8+e][n = nb*64+nf*16+(lane&15)].
// A wave's B-fragment (t,nb,kc,kh,nf) is then 64 lanes x 16B contiguous.
__global__ __launch_bounds__(256) void cvt_weights_kernel(
    const float* __restrict__ w4, const float* __restrict__ w5,
    u16* __restrict__ wt4, u16* __restrict__ wt5) {
    int g = blockIdx.x * 256 + threadIdx.x;  // granule id, 90*8192 total
    int mat = g >> 13;
    int r = g & 8191;
    int nb = r >> 11;
    int kc = (r >> 9) & 3;
    int kh = (r >> 8) & 1;
    int nf = (r >> 6) & 3;
    int lane = r & 63;
    int c0 = kc * 64 + kh * 32 + (lane >> 4) * 8;
    int n = nb * 64 + nf * 16 + (lane & 15);
    const float* src = (mat < 45) ? (w4 + (size_t)mat * 65536)
                                  : (w5 + (size_t)(mat - 45) * 65536);
    u16* dst = ((mat < 45) ? (wt4 + (size_t)mat * 65536)
                           : (wt5 + (size_t)(mat - 45) * 65536)) +
               (size_t)r * 8;
    u16 v[8];
#pragma unroll
    for (int e = 0; e < 8; e++) v[e] = f2b(src[(c0 + e) * 256 + n]);
    *(uint4*)dst = *(const uint4*)v;
}

// ------------------------------ 3x3 conv -----------------------------------
// implicit GEMM: M = B*Hout*Wout, N = 256, K = 9*256. 128x128 tile, 4 waves,
// BK=64. A: LDS ring-3 (48KB, XOR-swizzled). B: fragment-layout weights,
// global->VGPR, 2 register sets, 2-step prefetch. Step s = t*4+kc:
//   wait vmcnt(12) [retire A(s)+B(s); A(s+1),B(s+1) in flight] (s>=35: 0)
//   s_barrier; issue A(s+2)->ring[(s+2)%3];
//   compute(s): 8 ds_read A-frags + 32 MFMA with Bset[s&1];
//   load B(s+2) -> Bset[s&1] (consumed regs; arrives before wait(s+2)).
template <int STRIDE, bool HAS_MASK, bool HAS_RES, bool HAS_F32OUT>
__global__ __launch_bounds__(256, 2) void conv3x3_kernel(
    const u16* __restrict__ in, const u16* __restrict__ wt,
    const u16* __restrict__ zeros, const float* __restrict__ gamma,
    const float* __restrict__ beta, const float* __restrict__ mask,
    const u16* __restrict__ res, u16* __restrict__ outb,
    float* __restrict__ outf, int Hin, int Win, int Hout, int Wout, int Bn) {
    const int M = Bn * Hout * Wout;
    const int HWo = Hout * Wout;
    const int HWi = Hin * Win;
    const int tid = threadIdx.x;
    const int lane = tid & 63, wid = tid >> 6;
    const int wr = wid >> 1, wc = wid & 1;
    const int nwg = gridDim.x;
    const int q = nwg >> 3, r = nwg & 7;
    const int xc = blockIdx.x & 7, jj = blockIdx.x >> 3;
    const int wg = (xc < r ? xc * (q + 1) : r * (q + 1) + (xc - r) * q) + jj;
    const int m0 = (wg >> 1) * 128;
    const int n0 = (wg & 1) * 128;

    __shared__ u16 SMEM[24576];  // 48 KiB: A ring 3 x 16KB
    const int lrow = lane >> 3;
    const int csw = (((lane & 7) ^ (lrow & 7)) << 3);

    int ppy[4], ppx[4], ppb[4];
    bool ppo[4];
#pragma unroll
    for (int j = 0; j < 4; j++) {
        int gp = m0 + wid * 32 + j * 8 + lrow;
        ppo[j] = gp < M;
        int g2 = ppo[j] ? gp : 0;
        int b = g2 / HWo;
        int rr = g2 - b * HWo;
        ppy[j] = rr / Wout;
        ppx[j] = rr - ppy[j] * Wout;
        ppb[j] = b;
    }
    // B fragment base: nb = n-block (64 ch) this wave covers
    const int nb = (n0 >> 6) + wc;
    const u16* wb = wt + (size_t)nb * 16384 + lane * 8;

#define MKPTR(dst, T)                                                         \
    do {                                                                      \
        int dy_ = (T) / 3 - 1, dx_ = (T) % 3 - 1;                             \
        _Pragma("unroll") for (int j = 0; j < 4; j++) {                       \
            int sy_ = ppy[j] * STRIDE + dy_;                                  \
            int sx_ = ppx[j] * STRIDE + dx_;                                  \
            bool ok_ = ppo[j] && sy_ >= 0 && sy_ < Hin && sx_ >= 0 &&         \
                       sx_ < Win;                                             \
            long long off_ =                                                  \
                ((long long)ppb[j] * HWi + (long long)sy_ * Win + sx_) * 256; \
            dst[j] = ok_ ? in + off_ + csw : zeros + csw;                     \
        }                                                                     \
    } while (0)

#define ISSUE_A(APTR, KC, SLOT)                                               \
    do {                                                                      \
        u16* dA_ = SMEM + (SLOT)*8192;                                        \
        _Pragma("unroll") for (int j = 0; j < 4; j++) {                       \
            GLD16(APTR[j] + (KC)*64, dA_ + (wid * 32 + j * 8) * 64);          \
        }                                                                     \
    } while (0)

    f32x4 acc[4][4];
#pragma unroll
    for (int m = 0; m < 4; m++)
#pragma unroll
        for (int n = 0; n < 4; n++) acc[m][n] = (f32x4)0.f;

    const int rA = lane & 15;
    const int kb = (lane >> 4) * 8;
    const int xk = (rA & 7) << 3;

    bf16x8 bS0[8], bS1[8];
    // B(tt,kk) -> dst set: 8 coalesced dwordx4, imm-offset addressing
    auto loadB = [&](bf16x8(&dst)[8], int tt, int kk) {
        const u16* base = wb + tt * 65536 + kk * 4096;
#pragma unroll
        for (int nf = 0; nf < 4; nf++)
#pragma unroll
            for (int kh = 0; kh < 2; kh++)
                dst[nf * 2 + kh] =
                    *(const bf16x8*)(base + kh * 2048 + nf * 512);
    };
    // compute(s): A frags from ring slot, MFMA with given B set
    auto stepc = [&](const u16* Ar, const bf16x8(&bu)[8]) {
#pragma unroll
        for (int kh = 0; kh < 2; kh++) {
            bf16x8 af[4];
#pragma unroll
            for (int m = 0; m < 4; m++)
                af[m] = *(const bf16x8*)(Ar + (wr * 64 + m * 16 + rA) * 64 +
                                         ((kh * 32 + kb) ^ xk));
            __builtin_amdgcn_s_setprio(1);
#pragma unroll
            for (int m = 0; m < 4; m++)
#pragma unroll
                for (int n = 0; n < 4; n++)
                    acc[m][n] = __builtin_amdgcn_mfma_f32_16x16x32_bf16(
                        af[m], bu[n * 2 + kh], acc[m][n], 0, 0, 0);
            __builtin_amdgcn_s_setprio(0);
        }
    };

    const u16* aptrc[4];
    const u16* aptrn[4];
    MKPTR(aptrc, 0);
    // prologue, issue order = ledger order: A(0),B(0),A(1),B(1)
    ISSUE_A(aptrc, 0, 0);
    SB0;
    loadB(bS0, 0, 0);
    SB0;
    ISSUE_A(aptrc, 1, 1);
    SB0;
    loadB(bS1, 0, 1);
    SB0;

    int b0 = 0;  // t % 3

#pragma unroll 1
    for (int t = 0; t < 9; t++) {
        MKPTR(aptrn, t + 1);
#pragma unroll
        for (int kc = 0; kc < 4; kc++) {
            const int s = t * 4 + kc;
            int ib = b0 + kc;  // s % 3
            if (ib >= 3) ib -= 3;
            // retire A(s)+B(s) (oldest 12 of 24); keep A(s+1),B(s+1) in flight
            if (s < 35) {
                asm volatile("s_waitcnt vmcnt(12)" ::: "memory");
            } else {
                asm volatile("s_waitcnt vmcnt(0)" ::: "memory");
            }
            SB0;
            __builtin_amdgcn_s_barrier();
            SB0;
            // issue A(s+2) -> slot (s+2)%3 (readers finished at barrier(s))
            if (s < 34) {
                int ia = ib + 2;
                if (ia >= 3) ia -= 3;
                if (kc < 2) {
                    ISSUE_A(aptrc, kc + 2, ia);
                } else {
                    ISSUE_A(aptrn, kc - 2, ia);
                }
            }
            SB0;
            const u16* Ar = SMEM + ib * 8192;
            if (kc & 1) {
                stepc(Ar, bS1);
            } else {
                stepc(Ar, bS0);
            }
            SB0;
            // load B(s+2) into the set just consumed (parity (s+2)&1 == s&1)
            if (s < 34) {
                const int tB = (kc < 2) ? t : t + 1;
                const int kB = (kc < 2) ? kc + 2 : kc - 2;
                if (kc & 1) {
                    loadB(bS1, tB, kB);
                } else {
                    loadB(bS0, tB, kB);
                }
            }
            SB0;
        }
#pragma unroll
        for (int j = 0; j < 4; j++) aptrc[j] = aptrn[j];
        b0 = (b0 == 2) ? 0 : b0 + 1;
    }

    // ---------------- epilogue via LDS transpose (stride-66 pad) -----------
    __syncthreads();
    float* ep = (float*)SMEM + wid * 2112;  // 32 px x 66 f32 per wave (33.8KB)
    const int cb = n0 + wc * 64;
    float gms[4], bts[4];
#pragma unroll
    for (int n = 0; n < 4; n++) {
        gms[n] = gamma[cb + n * 16 + rA];
        bts[n] = beta[cb + n * 16 + rA];
    }
#pragma unroll
    for (int half = 0; half < 2; half++) {
#pragma unroll
        for (int m2 = 0; m2 < 2; m2++) {
            const int m = half * 2 + m2;
            const int lrb = m2 * 16 + ((lane >> 4) << 2);
            const int gpb = m0 + wr * 64 + half * 32 + lrb;
#pragma unroll
            for (int rr = 0; rr < 4; rr++) {
                float mk = 1.f;
                if (HAS_MASK) mk = (gpb + rr < M) ? mask[gpb + rr] : 0.f;
#pragma unroll
                for (int n = 0; n < 4; n++) {
                    float v = acc[m][n][rr] * gms[n] + bts[n];
                    if (HAS_MASK) v *= mk;
                    ep[(lrb + rr) * 66 + n * 16 + rA] = v;
                }
            }
        }
#pragma unroll
        for (int i = 0; i < 8; i++) {
            const int lr = i * 4 + (lane >> 4);
            const int gp = m0 + wr * 64 + half * 32 + lr;
            f32x4 v = *(const f32x4*)(ep + lr * 66 + rA * 4);
            if (HAS_RES && gp < M) {
                uint2 rv = *(const uint2*)(res + (size_t)gp * 256 + cb + rA * 4);
                v[0] += b2f((u16)(rv.x & 0xffff));
                v[1] += b2f((u16)(rv.x >> 16));
                v[2] += b2f((u16)(rv.y & 0xffff));
                v[3] += b2f((u16)(rv.y >> 16));
            }
            v[0] = fmaxf(v[0], 0.f);
            v[1] = fmaxf(v[1], 0.f);
            v[2] = fmaxf(v[2], 0.f);
            v[3] = fmaxf(v[3], 0.f);
            if (HAS_F32OUT) *(f32x4*)(ep + lr * 66 + rA * 4) = v;
            if (gp < M) {
                unsigned lo = (unsigned)f2b(v[0]) | ((unsigned)f2b(v[1]) << 16);
                unsigned hi = (unsigned)f2b(v[2]) | ((unsigned)f2b(v[3]) << 16);
                *(uint2*)(outb + (size_t)gp * 256 + cb + rA * 4) =
                    make_uint2(lo, hi);
            }
        }
        if (HAS_F32OUT) {
#pragma unroll
            for (int i = 0; i < 16; i++) {
                const int lc = i * 4 + (lane >> 4);
                const int p0 = rA * 2;
                const int gp0 = m0 + wr * 64 + half * 32 + p0;
                if (gp0 < M) {
                    float v0 = ep[p0 * 66 + lc];
                    float v1 = ep[(p0 + 1) * 66 + lc];
                    int b = gp0 / HWo;
                    int rr = gp0 - b * HWo;
                    const int ch = cb + lc;
                    float* o = outf + ((size_t)(b * 256 + ch)) * HWo + rr;
                    *(float2*)o = make_float2(v0, v1);
                }
            }
        }
    }
#undef MKPTR
#undef ISSUE_A
}

// ---------------------------------------------------------------------------
extern "C" void kernel_launch(void* const* d_in, const int* in_sizes, int n_in,
                              void* d_out, int out_size, void* d_ws,
                              size_t ws_size, hipStream_t stream) {
    const float* xyz = (const float*)d_in[0];
    const float* ptf = (const float*)d_in[1];
    const int* cnt = (const int*)d_in[2];
    const float* mw = (const float*)d_in[3];
    const float* mg = (const float*)d_in[4];
    const float* mb = (const float*)d_in[5];
    const float* c4w = (const float*)d_in[6];
    const float* c4g = (const float*)d_in[7];
    const float* c4b = (const float*)d_in[8];
    const float* c5w = (const float*)d_in[9];
    const float* c5g = (const float*)d_in[10];
    const float* c5b = (const float*)d_in[11];
    const int N = in_sizes[0] / 3;

    char* ws = (char*)d_ws;
    int* pcnt = (int*)ws;               //         0 :   282,752
    u16* zeros = (u16*)(ws + 282752);   //   282,752 :       512
    float* occ = (float*)(ws + 283264); //   283,264 :   282,752
    int* plist = (int*)(ws + 566016);   //   566,016 : 9,048,064
    u16* wt4 = (u16*)(ws + 9614080);
    u16* wt5 = (u16*)(ws + 15512320);
    u16* bufA = (u16*)(ws + 21410560);
    u16* bufB = (u16*)(ws + 57602816);
    u16* bufC = (u16*)(ws + 93795072);

    float* outXC4 = (float*)d_out;
    float* outY = ((float*)d_out) + 18096128;

    const int M188 = 2 * 188 * 188;  // 70688
    const int M94 = 2 * 94 * 94;     // 17672

    hipMemsetAsync(ws, 0, 283264, stream);
    cvt_weights_kernel<<<2880, 256, 0, stream>>>(c4w, c5w, wt4, wt5);
    bin_kernel<<<(N + 255) / 256, 256, 0, stream>>>(xyz, cnt, pcnt, plist, N);
    pillar_kernel<<<M188 / 4, 256, 0, stream>>>(xyz, ptf, mw, mg, mb, pcnt,
                                                plist, bufA, occ);

    dim3 g188(2 * ((M188 + 127) / 128)), g94(2 * ((M94 + 127) / 128));
    const size_t WL = 9 * 65536;

    // conv4 @188
    conv3x3_kernel<1, true, false, false><<<g188, 256, 0, stream>>>(
        bufA, wt4 + 0 * WL, zeros, c4g + 0, c4b + 0, occ, nullptr, bufB,
        nullptr, 188, 188, 188, 188, 2);
    conv3x3_kernel<1, true, false, false><<<g188, 256, 0, stream>>>(
        bufB, wt4 + 1 * WL, zeros, c4g + 256, c4b + 256, occ, nullptr, bufC,
        nullptr, 188, 188, 188, 188, 2);
    conv3x3_kernel<1, true, true, false><<<g188, 256, 0, stream>>>(
        bufC, wt4 + 2 * WL, zeros, c4g + 512, c4b + 512, occ, bufB, bufA,
        nullptr, 188, 188, 188, 188, 2);
    conv3x3_kernel<1, true, false, false><<<g188, 256, 0, stream>>>(
        bufA, wt4 + 3 * WL, zeros, c4g + 768, c4b + 768, occ, nullptr, bufC,
        nullptr, 188, 188, 188, 188, 2);
    conv3x3_kernel<1, true, true, true><<<g188, 256, 0, stream>>>(
        bufC, wt4 + 4 * WL, zeros, c4g + 1024, c4b + 1024, occ, bufA, bufB,
        outXC4, 188, 188, 188, 188, 2);

    // conv5 @94
    conv3x3_kernel<2, false, false, false><<<g94, 256, 0, stream>>>(
        bufB, wt5 + 0 * WL, zeros, c5g + 0, c5b + 0, nullptr, nullptr, bufA,
        nullptr, 188, 188, 94, 94, 2);
    conv3x3_kernel<1, false, false, false><<<g94, 256, 0, stream>>>(
        bufA, wt5 + 1 * WL, zeros, c5g + 256, c5b + 256, nullptr, nullptr,
        bufC, nullptr, 94, 94, 94, 94, 2);
    conv3x3_kernel<1, false, true, false><<<g94, 256, 0, stream>>>(
        bufC, wt5 + 2 * WL, zeros, c5g + 512, c5b + 512, nullptr, bufA, bufB,
        nullptr, 94, 94, 94, 94, 2);
    conv3x3_kernel<1, false, false, false><<<g94, 256, 0, stream>>>(
        bufB, wt5 + 3 * WL, zeros, c5g + 768, c5b + 768, nullptr, nullptr,
        bufC, nullptr, 94, 94, 94, 94, 2);
    conv3x3_kernel<1, false, true, true><<<g94, 256, 0, stream>>>(
        bufC, wt5 + 4 * WL, zeros, c5g + 1024, c5b + 1024, nullptr, bufB,
        bufA, outY, 94, 94, 94, 94, 2);
}

// Round 11
// 902.459 us; speedup vs baseline: 1.0016x; 1.0016x over previous
//
#include <hip/hip_runtime.h>
#include <hip/hip_bf16.h>

// ---------------------------------------------------------------------------
// SpMiddlePillarEncoder8x18. Round 11 = Round 10 with the B-register spill
// fixed: the lambda-by-reference array (alloca -> scratch, VGPR=108) is
// replaced by 16 NAMED bf16x8 registers + macros. B weights stay in the
// fragment-order layout (global->VGPR, coalesced, double-buffered, 2-step
// prefetch); A stays in a 3-slot LDS ring (48KB). Per step: wait vmcnt(12)
// [retires A(s)+B(s); A(s+1),B(s+1) in flight across barrier]; barrier;
// issue A(s+2); compute(s); load B(s+2).
// ---------------------------------------------------------------------------

typedef __attribute__((ext_vector_type(8))) short bf16x8;
typedef __attribute__((ext_vector_type(4))) float f32x4;
typedef unsigned short u16;

#define GLD16(g, l)                                                   \
    __builtin_amdgcn_global_load_lds(                                 \
        (const __attribute__((address_space(1))) void*)(g),           \
        (__attribute__((address_space(3))) void*)(l), 16, 0, 0)

#define SB0 __builtin_amdgcn_sched_barrier(0)
#define MFMA16(a, b, c) __builtin_amdgcn_mfma_f32_16x16x32_bf16((a), (b), (c), 0, 0, 0)

__device__ __forceinline__ u16 f2b(float f) {
    unsigned u = __float_as_uint(f);
    u += 0x7fffu + ((u >> 16) & 1u);  // round-to-nearest-even
    return (u16)(u >> 16);
}
__device__ __forceinline__ float b2f(u16 h) {
    return __uint_as_float(((unsigned)h) << 16);
}

// ------------------------------- binning -----------------------------------
__global__ __launch_bounds__(256) void bin_kernel(
    const float* __restrict__ xyz, const int* __restrict__ cnt,
    int* __restrict__ pcnt, int* __restrict__ plist, int N) {
    int i = blockIdx.x * 256 + threadIdx.x;
    if (i >= N) return;
    float x = xyz[3 * i], y = xyz[3 * i + 1];
    int b = (i < cnt[0]) ? 0 : 1;
    int ix = (int)floorf((x + 75.2f) / 0.8f);
    int iy = (int)floorf((y + 75.2f) / 0.8f);
    ix = min(max(ix, 0), 187);
    iy = min(max(iy, 0), 187);
    int flat = (b * 188 + iy) * 188 + ix;
    int slot = atomicAdd(pcnt + flat, 1);
    if (slot < 32) plist[flat * 32 + slot] = i;
}

// --------------------------- pillar MLP + max ------------------------------
__global__ __launch_bounds__(256) void pillar_kernel(
    const float* __restrict__ xyz, const float* __restrict__ ptf,
    const float* __restrict__ mw, const float* __restrict__ mg,
    const float* __restrict__ mb, const int* __restrict__ pcnt,
    const int* __restrict__ plist, u16* __restrict__ out,
    float* __restrict__ occ) {
    const int lane = threadIdx.x & 63, wid = threadIdx.x >> 6;
    const int p = blockIdx.x * 4 + wid;
    const int n = min(pcnt[p], 32);
    const int c = lane * 4;
    float m0 = 0.f, m1 = 0.f, m2 = 0.f, m3 = 0.f;
    if (n > 0) {
        const int ix = p % 188;
        const int iy = (p / 188) % 188;
        const float cx = -75.2f + ((float)ix + 0.5f) * 0.8f;
        const float cy = -75.2f + ((float)iy + 0.5f) * 0.8f;
        float4 w[8];
#pragma unroll
        for (int k = 0; k < 8; k++) w[k] = *(const float4*)(mw + k * 256 + c);
        for (int t = 0; t < n; t++) {
            int i = __builtin_amdgcn_readfirstlane(plist[p * 32 + t]);
            float x = xyz[3 * i], y = xyz[3 * i + 1], z = xyz[3 * i + 2];
            float f0 = ptf[2 * i], f1 = ptf[2 * i + 1];
            const float f[8] = {x, y, z, x - cx, y - cy, z, f0, f1};
            float s0 = 0.f, s1 = 0.f, s2 = 0.f, s3 = 0.f;
#pragma unroll
            for (int k = 0; k < 8; k++) {
                s0 = fmaf(f[k], w[k].x, s0);
                s1 = fmaf(f[k], w[k].y, s1);
                s2 = fmaf(f[k], w[k].z, s2);
                s3 = fmaf(f[k], w[k].w, s3);
            }
            float4 g4 = *(const float4*)(mg + c);
            float4 b4 = *(const float4*)(mb + c);
            m0 = fmaxf(m0, fmaxf(s0 * g4.x + b4.x, 0.f));
            m1 = fmaxf(m1, fmaxf(s1 * g4.y + b4.y, 0.f));
            m2 = fmaxf(m2, fmaxf(s2 * g4.z + b4.z, 0.f));
            m3 = fmaxf(m3, fmaxf(s3 * g4.w + b4.w, 0.f));
        }
    }
    unsigned lo = (unsigned)f2b(m0) | ((unsigned)f2b(m1) << 16);
    unsigned hi = (unsigned)f2b(m2) | ((unsigned)f2b(m3) << 16);
    *(uint2*)(out + (size_t)p * 256 + c) = make_uint2(lo, hi);
    if (lane == 0) occ[p] = (n > 0) ? 1.f : 0.f;
}

// ---------------- weight convert into FRAGMENT layout (once) ---------------
// src: [mat][c][n] f32 (mat = layer*9+tap). dst (per mat, 65536 u16):
// elem off = nb*16384 + kc*4096 + kh*2048 + nf*512 + lane*8 + e  holds
// W[c = kc*64+kh*32+(lane>>4)*8+e][n = nb*64+nf*16+(lane&15)].
__global__ __launch_bounds__(256) void cvt_weights_kernel(
    const float* __restrict__ w4, const float* __restrict__ w5,
    u16* __restrict__ wt4, u16* __restrict__ wt5) {
    int g = blockIdx.x * 256 + threadIdx.x;  // granule id, 90*8192 total
    int mat = g >> 13;
    int r = g & 8191;
    int nb = r >> 11;
    int kc = (r >> 9) & 3;
    int kh = (r >> 8) & 1;
    int nf = (r >> 6) & 3;
    int lane = r & 63;
    int c0 = kc * 64 + kh * 32 + (lane >> 4) * 8;
    int n = nb * 64 + nf * 16 + (lane & 15);
    const float* src = (mat < 45) ? (w4 + (size_t)mat * 65536)
                                  : (w5 + (size_t)(mat - 45) * 65536);
    u16* dst = ((mat < 45) ? (wt4 + (size_t)mat * 65536)
                           : (wt5 + (size_t)(mat - 45) * 65536)) +
               (size_t)r * 8;
    u16 v[8];
#pragma unroll
    for (int e = 0; e < 8; e++) v[e] = f2b(src[(c0 + e) * 256 + n]);
    *(uint4*)dst = *(const uint4*)v;
}

// ------------------------------ 3x3 conv -----------------------------------
// implicit GEMM: M = B*Hout*Wout, N = 256, K = 9*256. 128x128 tile, 4 waves,
// BK=64. A: LDS ring-3 (48KB, XOR-swizzled). B: fragment-layout weights in
// 16 NAMED bf16x8 registers (two sets), 2-step prefetch. Step s = t*4+kc:
//   wait vmcnt(12) [retire A(s)+B(s); A(s+1),B(s+1) in flight] (s>=35: 0)
//   s_barrier; issue A(s+2)->ring[(s+2)%3];
//   compute(s): 8 ds_read A-frags + 32 MFMA with set[s&1];
//   load B(s+2) -> set[s&1] (regs just consumed).
template <int STRIDE, bool HAS_MASK, bool HAS_RES, bool HAS_F32OUT>
__global__ __launch_bounds__(256, 2) void conv3x3_kernel(
    const u16* __restrict__ in, const u16* __restrict__ wt,
    const u16* __restrict__ zeros, const float* __restrict__ gamma,
    const float* __restrict__ beta, const float* __restrict__ mask,
    const u16* __restrict__ res, u16* __restrict__ outb,
    float* __restrict__ outf, int Hin, int Win, int Hout, int Wout, int Bn) {
    const int M = Bn * Hout * Wout;
    const int HWo = Hout * Wout;
    const int HWi = Hin * Win;
    const int tid = threadIdx.x;
    const int lane = tid & 63, wid = tid >> 6;
    const int wr = wid >> 1, wc = wid & 1;
    const int nwg = gridDim.x;
    const int q = nwg >> 3, r = nwg & 7;
    const int xc = blockIdx.x & 7, jj = blockIdx.x >> 3;
    const int wg = (xc < r ? xc * (q + 1) : r * (q + 1) + (xc - r) * q) + jj;
    const int m0 = (wg >> 1) * 128;
    const int n0 = (wg & 1) * 128;

    __shared__ u16 SMEM[24576];  // 48 KiB: A ring 3 x 16KB
    const int lrow = lane >> 3;
    const int csw = (((lane & 7) ^ (lrow & 7)) << 3);

    int ppy[4], ppx[4], ppb[4];
    bool ppo[4];
#pragma unroll
    for (int j = 0; j < 4; j++) {
        int gp = m0 + wid * 32 + j * 8 + lrow;
        ppo[j] = gp < M;
        int g2 = ppo[j] ? gp : 0;
        int b = g2 / HWo;
        int rr = g2 - b * HWo;
        ppy[j] = rr / Wout;
        ppx[j] = rr - ppy[j] * Wout;
        ppb[j] = b;
    }
    // B fragment base: nb = n-block (64 ch) this wave covers
    const int nb = (n0 >> 6) + wc;
    const u16* wb = wt + (size_t)nb * 16384 + lane * 8;

#define MKPTR(dst, T)                                                         \
    do {                                                                      \
        int dy_ = (T) / 3 - 1, dx_ = (T) % 3 - 1;                             \
        _Pragma("unroll") for (int j = 0; j < 4; j++) {                       \
            int sy_ = ppy[j] * STRIDE + dy_;                                  \
            int sx_ = ppx[j] * STRIDE + dx_;                                  \
            bool ok_ = ppo[j] && sy_ >= 0 && sy_ < Hin && sx_ >= 0 &&         \
                       sx_ < Win;                                             \
            long long off_ =                                                  \
                ((long long)ppb[j] * HWi + (long long)sy_ * Win + sx_) * 256; \
            dst[j] = ok_ ? in + off_ + csw : zeros + csw;                     \
        }                                                                     \
    } while (0)

#define ISSUE_A(APTR, KC, SLOT)                                               \
    do {                                                                      \
        u16* dA_ = SMEM + (SLOT)*8192;                                        \
        _Pragma("unroll") for (int j = 0; j < 4; j++) {                       \
            GLD16(APTR[j] + (KC)*64, dA_ + (wid * 32 + j * 8) * 64);          \
        }                                                                     \
    } while (0)

// B(tt,kk) -> named register set (8 coalesced 16B loads, imm offsets).
// Index nf*2+kh lives at elem offset kh*2048 + nf*512.
#define LOADB(SET, tt, kk)                                                    \
    do {                                                                      \
        const u16* base_ = wb + (tt)*65536 + (kk)*4096;                       \
        SET##0 = *(const bf16x8*)(base_);                                     \
        SET##1 = *(const bf16x8*)(base_ + 2048);                              \
        SET##2 = *(const bf16x8*)(base_ + 512);                               \
        SET##3 = *(const bf16x8*)(base_ + 2560);                              \
        SET##4 = *(const bf16x8*)(base_ + 1024);                              \
        SET##5 = *(const bf16x8*)(base_ + 3072);                              \
        SET##6 = *(const bf16x8*)(base_ + 1536);                              \
        SET##7 = *(const bf16x8*)(base_ + 3584);                              \
    } while (0)

// compute(s): A frags from ring slot (XOR-swizzled), 32 MFMA with SET regs
#define STEPC(SET)                                                            \
    do {                                                                      \
        bf16x8 af_[4];                                                        \
        _Pragma("unroll") for (int m_ = 0; m_ < 4; m_++) af_[m_] =            \
            *(const bf16x8*)(Ar + (wr * 64 + m_ * 16 + rA) * 64 + (kb ^ xk)); \
        __builtin_amdgcn_s_setprio(1);                                        \
        _Pragma("unroll") for (int m_ = 0; m_ < 4; m_++) {                    \
            acc[m_][0] = MFMA16(af_[m_], SET##0, acc[m_][0]);                 \
            acc[m_][1] = MFMA16(af_[m_], SET##2, acc[m_][1]);                 \
            acc[m_][2] = MFMA16(af_[m_], SET##4, acc[m_][2]);                 \
            acc[m_][3] = MFMA16(af_[m_], SET##6, acc[m_][3]);                 \
        }                                                                     \
        __builtin_amdgcn_s_setprio(0);                                        \
        _Pragma("unroll") for (int m_ = 0; m_ < 4; m_++) af_[m_] =            \
            *(const bf16x8*)(Ar + (wr * 64 + m_ * 16 + rA) * 64 +             \
                             ((32 + kb) ^ xk));                               \
        __builtin_amdgcn_s_setprio(1);                                        \
        _Pragma("unroll") for (int m_ = 0; m_ < 4; m_++) {                    \
            acc[m_][0] = MFMA16(af_[m_], SET##1, acc[m_][0]);                 \
            acc[m_][1] = MFMA16(af_[m_], SET##3, acc[m_][1]);                 \
            acc[m_][2] = MFMA16(af_[m_], SET##5, acc[m_][2]);                 \
            acc[m_][3] = MFMA16(af_[m_], SET##7, acc[m_][3]);                 \
        }                                                                     \
        __builtin_amdgcn_s_setprio(0);                                        \
    } while (0)

    f32x4 acc[4][4];
#pragma unroll
    for (int m = 0; m < 4; m++)
#pragma unroll
        for (int n = 0; n < 4; n++) acc[m][n] = (f32x4)0.f;

    const int rA = lane & 15;
    const int kb = (lane >> 4) * 8;
    const int xk = (rA & 7) << 3;

    bf16x8 bA0, bA1, bA2, bA3, bA4, bA5, bA6, bA7;  // B set, even steps
    bf16x8 bB0, bB1, bB2, bB3, bB4, bB5, bB6, bB7;  // B set, odd steps

    const u16* aptrc[4];
    const u16* aptrn[4];
    MKPTR(aptrc, 0);
    // prologue, issue order = ledger order: A(0), B(0), A(1), B(1)
    ISSUE_A(aptrc, 0, 0);
    SB0;
    LOADB(bA, 0, 0);
    SB0;
    ISSUE_A(aptrc, 1, 1);
    SB0;
    LOADB(bB, 0, 1);
    SB0;

    int b0 = 0;  // t % 3

#pragma unroll 1
    for (int t = 0; t < 9; t++) {
        MKPTR(aptrn, t + 1);
#pragma unroll
        for (int kc = 0; kc < 4; kc++) {
            const int s = t * 4 + kc;
            int ib = b0 + kc;  // s % 3
            if (ib >= 3) ib -= 3;
            // retire A(s)+B(s) (oldest 12 of 24); keep A(s+1),B(s+1) in flight
            if (s < 35) {
                asm volatile("s_waitcnt vmcnt(12)" ::: "memory");
            } else {
                asm volatile("s_waitcnt vmcnt(0)" ::: "memory");
            }
            SB0;
            __builtin_amdgcn_s_barrier();
            SB0;
            // issue A(s+2) -> slot (s+2)%3 (readers finished at barrier(s))
            if (s < 34) {
                int ia = ib + 2;
                if (ia >= 3) ia -= 3;
                if (kc < 2) {
                    ISSUE_A(aptrc, kc + 2, ia);
                } else {
                    ISSUE_A(aptrn, kc - 2, ia);
                }
            }
            SB0;
            const u16* Ar = SMEM + ib * 8192;
            if (kc & 1) {
                STEPC(bB);
            } else {
                STEPC(bA);
            }
            SB0;
            // load B(s+2) into the set just consumed ((s+2)&1 == s&1)
            if (s < 34) {
                const int tB = (kc < 2) ? t : t + 1;
                const int kB = (kc < 2) ? kc + 2 : kc - 2;
                if (kc & 1) {
                    LOADB(bB, tB, kB);
                } else {
                    LOADB(bA, tB, kB);
                }
            }
            SB0;
        }
#pragma unroll
        for (int j = 0; j < 4; j++) aptrc[j] = aptrn[j];
        b0 = (b0 == 2) ? 0 : b0 + 1;
    }

    // ---------------- epilogue via LDS transpose (stride-66 pad) -----------
    __syncthreads();
    float* ep = (float*)SMEM + wid * 2112;  // 32 px x 66 f32 per wave (33.8KB)
    const int cb = n0 + wc * 64;
    float gms[4], bts[4];
#pragma unroll
    for (int n = 0; n < 4; n++) {
        gms[n] = gamma[cb + n * 16 + rA];
        bts[n] = beta[cb + n * 16 + rA];
    }
#pragma unroll
    for (int half = 0; half < 2; half++) {
#pragma unroll
        for (int m2 = 0; m2 < 2; m2++) {
            const int m = half * 2 + m2;
            const int lrb = m2 * 16 + ((lane >> 4) << 2);
            const int gpb = m0 + wr * 64 + half * 32 + lrb;
#pragma unroll
            for (int rr = 0; rr < 4; rr++) {
                float mk = 1.f;
                if (HAS_MASK) mk = (gpb + rr < M) ? mask[gpb + rr] : 0.f;
#pragma unroll
                for (int n = 0; n < 4; n++) {
                    float v = acc[m][n][rr] * gms[n] + bts[n];
                    if (HAS_MASK) v *= mk;
                    ep[(lrb + rr) * 66 + n * 16 + rA] = v;
                }
            }
        }
#pragma unroll
        for (int i = 0; i < 8; i++) {
            const int lr = i * 4 + (lane >> 4);
            const int gp = m0 + wr * 64 + half * 32 + lr;
            f32x4 v = *(const f32x4*)(ep + lr * 66 + rA * 4);
            if (HAS_RES && gp < M) {
                uint2 rv = *(const uint2*)(res + (size_t)gp * 256 + cb + rA * 4);
                v[0] += b2f((u16)(rv.x & 0xffff));
                v[1] += b2f((u16)(rv.x >> 16));
                v[2] += b2f((u16)(rv.y & 0xffff));
                v[3] += b2f((u16)(rv.y >> 16));
            }
            v[0] = fmaxf(v[0], 0.f);
            v[1] = fmaxf(v[1], 0.f);
            v[2] = fmaxf(v[2], 0.f);
            v[3] = fmaxf(v[3], 0.f);
            if (HAS_F32OUT) *(f32x4*)(ep + lr * 66 + rA * 4) = v;
            if (gp < M) {
                unsigned lo = (unsigned)f2b(v[0]) | ((unsigned)f2b(v[1]) << 16);
                unsigned hi = (unsigned)f2b(v[2]) | ((unsigned)f2b(v[3]) << 16);
                *(uint2*)(outb + (size_t)gp * 256 + cb + rA * 4) =
                    make_uint2(lo, hi);
            }
        }
        if (HAS_F32OUT) {
#pragma unroll
            for (int i = 0; i < 16; i++) {
                const int lc = i * 4 + (lane >> 4);
                const int p0 = rA * 2;
                const int gp0 = m0 + wr * 64 + half * 32 + p0;
                if (gp0 < M) {
                    float v0 = ep[p0 * 66 + lc];
                    float v1 = ep[(p0 + 1) * 66 + lc];
                    int b = gp0 / HWo;
                    int rr = gp0 - b * HWo;
                    const int ch = cb + lc;
                    float* o = outf + ((size_t)(b * 256 + ch)) * HWo + rr;
                    *(float2*)o = make_float2(v0, v1);
                }
            }
        }
    }
#undef MKPTR
#undef ISSUE_A
#undef LOADB
#undef STEPC
}

// ---------------------------------------------------------------------------
extern "C" void kernel_launch(void* const* d_in, const int* in_sizes, int n_in,
                              void* d_out, int out_size, void* d_ws,
                              size_t ws_size, hipStream_t stream) {
    const float* xyz = (const float*)d_in[0];
    const float* ptf = (const float*)d_in[1];
    const int* cnt = (const int*)d_in[2];
    const float* mw = (const float*)d_in[3];
    const float* mg = (const float*)d_in[4];
    const float* mb = (const float*)d_in[5];
    const float* c4w = (const float*)d_in[6];
    const float* c4g = (const float*)d_in[7];
    const float* c4b = (const float*)d_in[8];
    const float* c5w = (const float*)d_in[9];
    const float* c5g = (const float*)d_in[10];
    const float* c5b = (const float*)d_in[11];
    const int N = in_sizes[0] / 3;

    char* ws = (char*)d_ws;
    int* pcnt = (int*)ws;               //         0 :   282,752
    u16* zeros = (u16*)(ws + 282752);   //   282,752 :       512
    float* occ = (float*)(ws + 283264); //   283,264 :   282,752
    int* plist = (int*)(ws + 566016);   //   566,016 : 9,048,064
    u16* wt4 = (u16*)(ws + 9614080);
    u16* wt5 = (u16*)(ws + 15512320);
    u16* bufA = (u16*)(ws + 21410560);
    u16* bufB = (u16*)(ws + 57602816);
    u16* bufC = (u16*)(ws + 93795072);

    float* outXC4 = (float*)d_out;
    float* outY = ((float*)d_out) + 18096128;

    const int M188 = 2 * 188 * 188;  // 70688
    const int M94 = 2 * 94 * 94;     // 17672

    hipMemsetAsync(ws, 0, 283264, stream);
    cvt_weights_kernel<<<2880, 256, 0, stream>>>(c4w, c5w, wt4, wt5);
    bin_kernel<<<(N + 255) / 256, 256, 0, stream>>>(xyz, cnt, pcnt, plist, N);
    pillar_kernel<<<M188 / 4, 256, 0, stream>>>(xyz, ptf, mw, mg, mb, pcnt,
                                                plist, bufA, occ);

    dim3 g188(2 * ((M188 + 127) / 128)), g94(2 * ((M94 + 127) / 128));
    const size_t WL = 9 * 65536;

    // conv4 @188
    conv3x3_kernel<1, true, false, false><<<g188, 256, 0, stream>>>(
        bufA, wt4 + 0 * WL, zeros, c4g + 0, c4b + 0, occ, nullptr, bufB,
        nullptr, 188, 188, 188, 188, 2);
    conv3x3_kernel<1, true, false, false><<<g188, 256, 0, stream>>>(
        bufB, wt4 + 1 * WL, zeros, c4g + 256, c4b + 256, occ, nullptr, bufC,
        nullptr, 188, 188, 188, 188, 2);
    conv3x3_kernel<1, true, true, false><<<g188, 256, 0, stream>>>(
        bufC, wt4 + 2 * WL, zeros, c4g + 512, c4b + 512, occ, bufB, bufA,
        nullptr, 188, 188, 188, 188, 2);
    conv3x3_kernel<1, true, false, false><<<g188, 256, 0, stream>>>(
        bufA, wt4 + 3 * WL, zeros, c4g + 768, c4b + 768, occ, nullptr, bufC,
        nullptr, 188, 188, 188, 188, 2);
    conv3x3_kernel<1, true, true, true><<<g188, 256, 0, stream>>>(
        bufC, wt4 + 4 * WL, zeros, c4g + 1024, c4b + 1024, occ, bufA, bufB,
        outXC4, 188, 188, 188, 188, 2);

    // conv5 @94
    conv3x3_kernel<2, false, false, false><<<g94, 256, 0, stream>>>(
        bufB, wt5 + 0 * WL, zeros, c5g + 0, c5b + 0, nullptr, nullptr, bufA,
        nullptr, 188, 188, 94, 94, 2);
    conv3x3_kernel<1, false, false, false><<<g94, 256, 0, stream>>>(
        bufA, wt5 + 1 * WL, zeros, c5g + 256, c5b + 256, nullptr, nullptr,
        bufC, nullptr, 94, 94, 94, 94, 2);
    conv3x3_kernel<1, false, true, false><<<g94, 256, 0, stream>>>(
        bufC, wt5 + 2 * WL, zeros, c5g + 512, c5b + 512, nullptr, bufA, bufB,
        nullptr, 94, 94, 94, 94, 2);
    conv3x3_kernel<1, false, false, false><<<g94, 256, 0, stream>>>(
        bufB, wt5 + 3 * WL, zeros, c5g + 768, c5b + 768, nullptr, nullptr,
        bufC, nullptr, 94, 94, 94, 94, 2);
    conv3x3_kernel<1, false, true, true><<<g94, 256, 0, stream>>>(
        bufC, wt5 + 4 * WL, zeros, c5g + 1024, c5b + 1024, nullptr, bufB,
        bufA, outY, 94, 94, 94, 94, 2);
}